// Round 19
// baseline (198.954 us; speedup 1.0000x reference)
//
#include <hip/hip_runtime.h>
#include <hip/hip_bf16.h>

#define H_  128
#define B_  64
#define N_  100
#define M_  2000
#define NT  512

// ws layout (ushort units): per matrix, per 128-k window: 64 KB image =
// [hi plane 32 KB][lo plane 32 KB]; plane layout [k/8][n 0..127][8 k-elems]
// -> a wave W-frag read (lanes n-consecutive, 16 B each) is 512 B contiguous.
// R12+: W-hi only. R13+: pure-bf16 activations. R16: T1 XCD remap (FETCH
// 459->261 MB verified). R18: hw-packed bf16 cvt. R19: T5 setprio around MFMA.
#define RW1T 0         // 6 windows
#define RW2T 196608    // 1 window
#define CW1T 229376    // 4 windows
#define CW2T 360448    // 1
#define AW1T 393216    // 1
#define AW2T 425984    // 1
#define AW3T 458752    // 1
#define WIN_U 32768       // ushorts per 64 KB window image
#define PLANE_U 16384     // ushorts per 32 KB plane image

typedef __attribute__((ext_vector_type(8)))  __bf16 bf16x8;
typedef __attribute__((ext_vector_type(16))) float  f32x16;

__device__ __forceinline__ unsigned short f2bf(float f) {
    unsigned int u = __float_as_uint(f);
    u = (u + 0x7FFFu + ((u >> 16) & 1u)) >> 16;
    return (unsigned short)u;
}
__device__ __forceinline__ float bf2f(unsigned short h) {
    return __uint_as_float(((unsigned int)h) << 16);
}
// packed fp32x2 -> bf16x2 (RNE, same rounding as f2bf), compiler-scheduled
__device__ __forceinline__ unsigned cvt2(float a, float b) {
    __hip_bfloat162 r = __float22bfloat162_rn(make_float2(a, b));
    return *(unsigned*)&r;
}

// -------- prep: build hi/lo W^T window images (frag-coalesced layout) --------
__global__ void __launch_bounds__(256)
wt_prep(const float* __restrict__ s0, const float* __restrict__ s1,
        const float* __restrict__ s2, const float* __restrict__ s3,
        const float* __restrict__ s4, const float* __restrict__ s5,
        const float* __restrict__ s6, unsigned short* __restrict__ wt)
{
    int g = blockIdx.x * 256 + threadIdx.x;
    if (g >= 245760) return;
    const float* src; int e, base;
    if      (g <  98304) { src = s0; e = g;          base = RW1T; }
    else if (g < 114688) { src = s1; e = g -  98304; base = RW2T; }
    else if (g < 180224) { src = s2; e = g - 114688; base = CW1T; }
    else if (g < 196608) { src = s3; e = g - 180224; base = CW2T; }
    else if (g < 212992) { src = s4; e = g - 196608; base = AW1T; }
    else if (g < 229376) { src = s5; e = g - 212992; base = AW2T; }
    else                 { src = s6; e = g - 229376; base = AW3T; }
    int k = e >> 7, n = e & 127;          // src is W[k][n], row-major n-contiguous
    float v = src[e];
    unsigned short hi = f2bf(v);
    unsigned short lo = f2bf(v - bf2f(hi));
    int w  = k >> 7, kk = k & 127;        // window, k-within-window
    size_t uoff = (size_t)base + (size_t)w * WIN_U
                + (size_t)((kk >> 3) * 128 + n) * 8 + (kk & 7);
    wt[uoff]           = hi;
    wt[uoff + PLANE_U] = lo;
}

// -------- main: R18 body + setprio(1) around the MFMA cluster --------
__global__ void __launch_bounds__(NT, 4)
vrp_mfma(const float* __restrict__ e_emb,
         const int* __restrict__ reloc_idx, const int* __restrict__ cross_idx,
         const int* __restrict__ twopt_idx,
         const float* __restrict__ reloc_b1, const float* __restrict__ reloc_b2,
         const float* __restrict__ cross_b1, const float* __restrict__ cross_b2,
         const float* __restrict__ an_b1, const float* __restrict__ an_b2,
         const float* __restrict__ an_b3,
         const float* __restrict__ an_Wo, const float* __restrict__ an_bo,
         const unsigned short* __restrict__ wt,
         float* __restrict__ out)
{
    __shared__ __align__(16) unsigned short Ah[H_ * H_];   // 32 KiB
    __shared__ __align__(16) float bias_all[6 * H_];
    __shared__ float red[4 * H_];

    const int t = threadIdx.x;
    // T1 XCD remap (bijective: 3072 = 8 * 384): each XCD owns 8 whole instances.
    const int phys = blockIdx.x;
    const int virt = (phys & 7) * 384 + (phys >> 3);
    const int b    = virt / 48;          // instance 0..63
    const int rem  = virt - b * 48;
    const int type    = rem >> 4;        // 0=reloc 1=cross 2=twopt
    const int blkTile = rem & 15;        // 128-move tile

    const int w    = t >> 6;            // wave 0..7
    const int l    = t & 63;
    const int l31  = l & 31;
    const int oct  = l >> 5;            // k-octet select
    const int ntile = w & 3;            // n-range ntile*32
    const int mhalf = w >> 2;           // m-range mhalf*64 (2 m-tiles)

    const int*  idxp = (type == 0) ? reloc_idx : (type == 1) ? cross_idx : twopt_idx;
    const int   KS   = (type == 0) ? 6 : 4;
    const int   w1t  = (type == 0) ? RW1T : CW1T;
    const int   w2t  = (type == 0) ? RW2T : CW2T;
    const float* b1p = (type == 0) ? reloc_b1 : cross_b1;
    const float* b2p = (type == 0) ? reloc_b2 : cross_b2;

    for (int i = t; i < 6 * H_; i += NT) {
        int g = i >> 7, ii = i & 127;
        const float* p = (g == 0) ? b1p : (g == 1) ? b2p : (g == 2) ? an_b1
                       : (g == 3) ? an_b2 : (g == 4) ? an_b3 : an_Wo;
        bias_all[i] = p[ii];
    }

    f32x16 acc0, acc1;
    #pragma unroll
    for (int i = 0; i < 16; ++i) { acc0[i] = 0.f; acc1[i] = 0.f; }

    auto zeroAcc = [&]() {
        #pragma unroll
        for (int i = 0; i < 16; ++i) { acc0[i] = 0.f; acc1[i] = 0.f; }
    };

    // T14 async-split gather: issue slot-s global loads into registers (vreg),
    // convert+write to LDS later (hides HBM/L2 latency under runUnit).
    float4 vreg[8];
    auto loadA = [&](int s) {
        #pragma unroll
        for (int it = 0; it < 8; ++it) {
            int c = t + NT * it;                // 4096 float4s
            int m = c >> 5, f4 = c & 31;
            int mg = blkTile * 128 + m; mg = (mg < M_) ? mg : (M_ - 1);
            const int* ip = idxp + (((b * M_ + mg) * KS + s) << 1);
            int ii = ip[0], jj = ip[1];
            vreg[it] = *((const float4*)(e_emb + (((size_t)b * N_ + ii) * N_ + jj) * H_) + f4);
        }
    };
    auto writeA = [&]() {
        #pragma unroll
        for (int it = 0; it < 8; ++it) {
            int c = t + NT * it;
            int m = c >> 5, f4 = c & 31;
            float4 v = vreg[it];
            uint2 hw;
            hw.x = cvt2(v.x, v.y);
            hw.y = cvt2(v.z, v.w);
            int off = m * 256 + ((f4 * 8) ^ ((m & 15) << 4));
            *(uint2*)((char*)Ah + off) = hw;
        }
    };

    // one K=128 unit: acc(+)= Wh_frag x actT_frag (C^T). Pure bf16 operands,
    // fp32 accumulate; W depth-1 prefetch from L2-hot coalesced image.
    // T5: raise wave priority across the MFMA cluster (phase-shifted blocks
    // on the CU are staging/converting meanwhile -> scheduler favors us).
    auto runUnit = [&](const unsigned short* win) {
        const char* wph = (const char*)win;
        const int nrow  = ntile * 32 + l31;
        const int wbase = nrow * 16 + oct * 2048;     // + ks*4096
        const int mrow  = mhalf * 64 + l31;
        const int mbase = mrow * 256, Xm = (mrow & 15) << 4;
        bf16x8 cwh = *(const bf16x8*)(wph + wbase);
        __builtin_amdgcn_s_setprio(1);
        #pragma unroll
        for (int ks = 0; ks < 8; ++ks) {
            bf16x8 nwh = cwh;
            if (ks < 7)
                nwh = *(const bf16x8*)(wph + wbase + (ks + 1) * 4096);
            int ka   = ks * 32 + oct * 16;
            int offA = mbase + (ka ^ Xm);
            bf16x8 a0 = *(const bf16x8*)((const char*)Ah + offA);
            bf16x8 a1 = *(const bf16x8*)((const char*)Ah + offA + 32 * 256);
            acc0 = __builtin_amdgcn_mfma_f32_32x32x16_bf16(cwh, a0, acc0, 0, 0, 0);
            acc1 = __builtin_amdgcn_mfma_f32_32x32x16_bf16(cwh, a1, acc1, 0, 0, 0);
            cwh = nwh;
        }
        __builtin_amdgcn_s_setprio(0);
    };

    // acc (=C^T: lane col = m, regs = n) -> bias/act -> bf16 -> Ah
    auto writeback = [&](int biasSlot, bool doRelu) {
        const float* bp = &bias_all[biasSlot * H_];
        #pragma unroll
        for (int tl = 0; tl < 2; ++tl) {
            int m  = mhalf * 64 + tl * 32 + l31;
            int mb = m * 256, Xm2 = (m & 15) << 4;
            #pragma unroll
            for (int q = 0; q < 4; ++q) {
                int n0 = ntile * 32 + q * 8 + oct * 4;   // 4 consecutive n
                float4 bq = *(const float4*)&bp[n0];
                float ba[4] = {bq.x, bq.y, bq.z, bq.w};
                float vv[4];
                #pragma unroll
                for (int r2 = 0; r2 < 4; ++r2) {
                    float v = (tl ? acc1[q * 4 + r2] : acc0[q * 4 + r2]) + ba[r2];
                    vv[r2] = doRelu ? fmaxf(v, 0.f) : v;
                }
                uint2 hw;
                hw.x = cvt2(vv[0], vv[1]);
                hw.y = cvt2(vv[2], vv[3]);
                int off = mb + ((n0 * 2) ^ Xm2);
                *(uint2*)((char*)Ah + off) = hw;
            }
        }
    };

    // ---- GEMM1: stream K over edge slots; next slot's loads fly under runUnit ----
    loadA(0);
    for (int s = 0; s < KS; ++s) {
        writeA();                       // LDS <- vreg (slot s)
        if (s + 1 < KS) loadA(s + 1);   // issue next slot's global loads early
        __syncthreads();
        runUnit(wt + w1t + s * WIN_U);
        __syncthreads();
    }
    // ---- chained 128x128 layers ----
    writeback(0, true);  __syncthreads(); zeroAcc(); runUnit(wt + w2t);  __syncthreads();
    writeback(1, false); __syncthreads(); zeroAcc(); runUnit(wt + AW1T); __syncthreads();
    writeback(2, true);  __syncthreads(); zeroAcc(); runUnit(wt + AW2T); __syncthreads();
    writeback(3, true);  __syncthreads(); zeroAcc(); runUnit(wt + AW3T); __syncthreads();

    // ---- final: logit = relu(acc + an_b3) . Wo + bo, straight from accumulators ----
    float p0 = 0.f, p1 = 0.f;
    {
        const float* b3p = &bias_all[4 * H_];
        const float* wop = &bias_all[5 * H_];
        #pragma unroll
        for (int q = 0; q < 4; ++q) {
            int n0 = ntile * 32 + q * 8 + oct * 4;
            float4 bq = *(const float4*)&b3p[n0];
            float4 wq = *(const float4*)&wop[n0];
            float ba[4] = {bq.x, bq.y, bq.z, bq.w};
            float wa[4] = {wq.x, wq.y, wq.z, wq.w};
            #pragma unroll
            for (int r2 = 0; r2 < 4; ++r2) {
                p0 += fmaxf(acc0[q * 4 + r2] + ba[r2], 0.f) * wa[r2];
                p1 += fmaxf(acc1[q * 4 + r2] + ba[r2], 0.f) * wa[r2];
            }
        }
    }
    p0 += __shfl_xor(p0, 32);
    p1 += __shfl_xor(p1, 32);
    if (l < 32) {
        red[ntile * H_ + mhalf * 64 + l31]      = p0;
        red[ntile * H_ + mhalf * 64 + 32 + l31] = p1;
    }
    __syncthreads();
    if (t < 128) {
        float sres = red[t] + red[H_ + t] + red[2 * H_ + t] + red[3 * H_ + t] + an_bo[0];
        int mg = blkTile * 128 + t;
        if (mg < M_)
            out[((size_t)(b * 3 + type)) * M_ + mg] = sres;
    }
}

extern "C" void kernel_launch(void* const* d_in, const int* in_sizes, int n_in,
                              void* d_out, int out_size, void* d_ws, size_t ws_size,
                              hipStream_t stream) {
    const float* e_emb     = (const float*)d_in[0];
    const int*   reloc_idx = (const int*)  d_in[1];
    const int*   cross_idx = (const int*)  d_in[2];
    const int*   twopt_idx = (const int*)  d_in[3];
    const float* reloc_W1  = (const float*)d_in[4];
    const float* reloc_b1  = (const float*)d_in[5];
    const float* reloc_W2  = (const float*)d_in[6];
    const float* reloc_b2  = (const float*)d_in[7];
    const float* cross_W1  = (const float*)d_in[8];
    const float* cross_b1  = (const float*)d_in[9];
    const float* cross_W2  = (const float*)d_in[10];
    const float* cross_b2  = (const float*)d_in[11];
    const float* an_W1     = (const float*)d_in[12];
    const float* an_b1     = (const float*)d_in[13];
    const float* an_W2     = (const float*)d_in[14];
    const float* an_b2     = (const float*)d_in[15];
    const float* an_W3     = (const float*)d_in[16];
    const float* an_b3     = (const float*)d_in[17];
    const float* an_Wo     = (const float*)d_in[18];
    const float* an_bo     = (const float*)d_in[19];
    float* out = (float*)d_out;
    unsigned short* wt = (unsigned short*)d_ws;   // needs ~983 KB of ws

    hipLaunchKernelGGL(wt_prep, dim3(960), dim3(256), 0, stream,
                       reloc_W1, reloc_W2, cross_W1, cross_W2, an_W1, an_W2, an_W3, wt);
    hipLaunchKernelGGL(vrp_mfma, dim3(3 * B_ * 16), dim3(NT), 0, stream,
                       e_emb, reloc_idx, cross_idx, twopt_idx,
                       reloc_b1, reloc_b2, cross_b1, cross_b2,
                       an_b1, an_b2, an_b3, an_Wo, an_bo, wt, out);
}

// Round 20
// 192.799 us; speedup vs baseline: 1.0319x; 1.0319x over previous
//
#include <hip/hip_runtime.h>
#include <hip/hip_bf16.h>

#define H_  128
#define B_  64
#define N_  100
#define M_  2000
#define NT  512

// ws layout (ushort units): per matrix, per 128-k window: 64 KB image =
// [hi plane 32 KB][lo plane 32 KB]; plane layout [k/8][n 0..127][8 k-elems]
// -> a wave W-frag read (lanes n-consecutive, 16 B each) is 512 B contiguous.
// Banked stack: MFMA C^T + W-hi-only (R12) + pure-bf16 acts (R13/R14) +
// coalesced W-from-L2 w/ prefetch (R9) + T14 async gather (R11) +
// T1 XCD remap (R16, FETCH 459->261 MB) + hw cvt_pk (R18).
// R19 setprio A/B: -2% -> reverted. This is the R18 configuration.
#define RW1T 0         // 6 windows
#define RW2T 196608    // 1 window
#define CW1T 229376    // 4 windows
#define CW2T 360448    // 1
#define AW1T 393216    // 1
#define AW2T 425984    // 1
#define AW3T 458752    // 1
#define WIN_U 32768       // ushorts per 64 KB window image
#define PLANE_U 16384     // ushorts per 32 KB plane image

typedef __attribute__((ext_vector_type(8)))  __bf16 bf16x8;
typedef __attribute__((ext_vector_type(16))) float  f32x16;

__device__ __forceinline__ unsigned short f2bf(float f) {
    unsigned int u = __float_as_uint(f);
    u = (u + 0x7FFFu + ((u >> 16) & 1u)) >> 16;
    return (unsigned short)u;
}
__device__ __forceinline__ float bf2f(unsigned short h) {
    return __uint_as_float(((unsigned int)h) << 16);
}
// packed fp32x2 -> bf16x2 (RNE, same rounding as f2bf), compiler-scheduled
__device__ __forceinline__ unsigned cvt2(float a, float b) {
    __hip_bfloat162 r = __float22bfloat162_rn(make_float2(a, b));
    return *(unsigned*)&r;
}

// -------- prep: build hi/lo W^T window images (frag-coalesced layout) --------
__global__ void __launch_bounds__(256)
wt_prep(const float* __restrict__ s0, const float* __restrict__ s1,
        const float* __restrict__ s2, const float* __restrict__ s3,
        const float* __restrict__ s4, const float* __restrict__ s5,
        const float* __restrict__ s6, unsigned short* __restrict__ wt)
{
    int g = blockIdx.x * 256 + threadIdx.x;
    if (g >= 245760) return;
    const float* src; int e, base;
    if      (g <  98304) { src = s0; e = g;          base = RW1T; }
    else if (g < 114688) { src = s1; e = g -  98304; base = RW2T; }
    else if (g < 180224) { src = s2; e = g - 114688; base = CW1T; }
    else if (g < 196608) { src = s3; e = g - 180224; base = CW2T; }
    else if (g < 212992) { src = s4; e = g - 196608; base = AW1T; }
    else if (g < 229376) { src = s5; e = g - 212992; base = AW2T; }
    else                 { src = s6; e = g - 229376; base = AW3T; }
    int k = e >> 7, n = e & 127;          // src is W[k][n], row-major n-contiguous
    float v = src[e];
    unsigned short hi = f2bf(v);
    unsigned short lo = f2bf(v - bf2f(hi));
    int w  = k >> 7, kk = k & 127;        // window, k-within-window
    size_t uoff = (size_t)base + (size_t)w * WIN_U
                + (size_t)((kk >> 3) * 128 + n) * 8 + (kk & 7);
    wt[uoff]           = hi;
    wt[uoff + PLANE_U] = lo;
}

// -------- main: R18 configuration (best measured: 194.2 us e2e) --------
__global__ void __launch_bounds__(NT, 4)
vrp_mfma(const float* __restrict__ e_emb,
         const int* __restrict__ reloc_idx, const int* __restrict__ cross_idx,
         const int* __restrict__ twopt_idx,
         const float* __restrict__ reloc_b1, const float* __restrict__ reloc_b2,
         const float* __restrict__ cross_b1, const float* __restrict__ cross_b2,
         const float* __restrict__ an_b1, const float* __restrict__ an_b2,
         const float* __restrict__ an_b3,
         const float* __restrict__ an_Wo, const float* __restrict__ an_bo,
         const unsigned short* __restrict__ wt,
         float* __restrict__ out)
{
    __shared__ __align__(16) unsigned short Ah[H_ * H_];   // 32 KiB
    __shared__ __align__(16) float bias_all[6 * H_];
    __shared__ float red[4 * H_];

    const int t = threadIdx.x;
    // T1 XCD remap (bijective: 3072 = 8 * 384): each XCD owns 8 whole instances.
    const int phys = blockIdx.x;
    const int virt = (phys & 7) * 384 + (phys >> 3);
    const int b    = virt / 48;          // instance 0..63
    const int rem  = virt - b * 48;
    const int type    = rem >> 4;        // 0=reloc 1=cross 2=twopt
    const int blkTile = rem & 15;        // 128-move tile

    const int w    = t >> 6;            // wave 0..7
    const int l    = t & 63;
    const int l31  = l & 31;
    const int oct  = l >> 5;            // k-octet select
    const int ntile = w & 3;            // n-range ntile*32
    const int mhalf = w >> 2;           // m-range mhalf*64 (2 m-tiles)

    const int*  idxp = (type == 0) ? reloc_idx : (type == 1) ? cross_idx : twopt_idx;
    const int   KS   = (type == 0) ? 6 : 4;
    const int   w1t  = (type == 0) ? RW1T : CW1T;
    const int   w2t  = (type == 0) ? RW2T : CW2T;
    const float* b1p = (type == 0) ? reloc_b1 : cross_b1;
    const float* b2p = (type == 0) ? reloc_b2 : cross_b2;

    for (int i = t; i < 6 * H_; i += NT) {
        int g = i >> 7, ii = i & 127;
        const float* p = (g == 0) ? b1p : (g == 1) ? b2p : (g == 2) ? an_b1
                       : (g == 3) ? an_b2 : (g == 4) ? an_b3 : an_Wo;
        bias_all[i] = p[ii];
    }

    f32x16 acc0, acc1;
    #pragma unroll
    for (int i = 0; i < 16; ++i) { acc0[i] = 0.f; acc1[i] = 0.f; }

    auto zeroAcc = [&]() {
        #pragma unroll
        for (int i = 0; i < 16; ++i) { acc0[i] = 0.f; acc1[i] = 0.f; }
    };

    // T14 async-split gather: issue slot-s global loads into registers (vreg),
    // convert+write to LDS later (hides HBM/L2 latency under runUnit).
    float4 vreg[8];
    auto loadA = [&](int s) {
        #pragma unroll
        for (int it = 0; it < 8; ++it) {
            int c = t + NT * it;                // 4096 float4s
            int m = c >> 5, f4 = c & 31;
            int mg = blkTile * 128 + m; mg = (mg < M_) ? mg : (M_ - 1);
            const int* ip = idxp + (((b * M_ + mg) * KS + s) << 1);
            int ii = ip[0], jj = ip[1];
            vreg[it] = *((const float4*)(e_emb + (((size_t)b * N_ + ii) * N_ + jj) * H_) + f4);
        }
    };
    auto writeA = [&]() {
        #pragma unroll
        for (int it = 0; it < 8; ++it) {
            int c = t + NT * it;
            int m = c >> 5, f4 = c & 31;
            float4 v = vreg[it];
            uint2 hw;
            hw.x = cvt2(v.x, v.y);
            hw.y = cvt2(v.z, v.w);
            int off = m * 256 + ((f4 * 8) ^ ((m & 15) << 4));
            *(uint2*)((char*)Ah + off) = hw;
        }
    };

    // one K=128 unit: acc(+)= Wh_frag x actT_frag (C^T). Pure bf16 operands,
    // fp32 accumulate; W depth-1 prefetch from L2-hot coalesced image.
    auto runUnit = [&](const unsigned short* win) {
        const char* wph = (const char*)win;
        const int nrow  = ntile * 32 + l31;
        const int wbase = nrow * 16 + oct * 2048;     // + ks*4096
        const int mrow  = mhalf * 64 + l31;
        const int mbase = mrow * 256, Xm = (mrow & 15) << 4;
        bf16x8 cwh = *(const bf16x8*)(wph + wbase);
        #pragma unroll
        for (int ks = 0; ks < 8; ++ks) {
            bf16x8 nwh = cwh;
            if (ks < 7)
                nwh = *(const bf16x8*)(wph + wbase + (ks + 1) * 4096);
            int ka   = ks * 32 + oct * 16;
            int offA = mbase + (ka ^ Xm);
            bf16x8 a0 = *(const bf16x8*)((const char*)Ah + offA);
            bf16x8 a1 = *(const bf16x8*)((const char*)Ah + offA + 32 * 256);
            acc0 = __builtin_amdgcn_mfma_f32_32x32x16_bf16(cwh, a0, acc0, 0, 0, 0);
            acc1 = __builtin_amdgcn_mfma_f32_32x32x16_bf16(cwh, a1, acc1, 0, 0, 0);
            cwh = nwh;
        }
    };

    // acc (=C^T: lane col = m, regs = n) -> bias/act -> bf16 -> Ah
    auto writeback = [&](int biasSlot, bool doRelu) {
        const float* bp = &bias_all[biasSlot * H_];
        #pragma unroll
        for (int tl = 0; tl < 2; ++tl) {
            int m  = mhalf * 64 + tl * 32 + l31;
            int mb = m * 256, Xm2 = (m & 15) << 4;
            #pragma unroll
            for (int q = 0; q < 4; ++q) {
                int n0 = ntile * 32 + q * 8 + oct * 4;   // 4 consecutive n
                float4 bq = *(const float4*)&bp[n0];
                float ba[4] = {bq.x, bq.y, bq.z, bq.w};
                float vv[4];
                #pragma unroll
                for (int r2 = 0; r2 < 4; ++r2) {
                    float v = (tl ? acc1[q * 4 + r2] : acc0[q * 4 + r2]) + ba[r2];
                    vv[r2] = doRelu ? fmaxf(v, 0.f) : v;
                }
                uint2 hw;
                hw.x = cvt2(vv[0], vv[1]);
                hw.y = cvt2(vv[2], vv[3]);
                int off = mb + ((n0 * 2) ^ Xm2);
                *(uint2*)((char*)Ah + off) = hw;
            }
        }
    };

    // ---- GEMM1: stream K over edge slots; next slot's loads fly under runUnit ----
    loadA(0);
    for (int s = 0; s < KS; ++s) {
        writeA();                       // LDS <- vreg (slot s)
        if (s + 1 < KS) loadA(s + 1);   // issue next slot's global loads early
        __syncthreads();
        runUnit(wt + w1t + s * WIN_U);
        __syncthreads();
    }
    // ---- chained 128x128 layers ----
    writeback(0, true);  __syncthreads(); zeroAcc(); runUnit(wt + w2t);  __syncthreads();
    writeback(1, false); __syncthreads(); zeroAcc(); runUnit(wt + AW1T); __syncthreads();
    writeback(2, true);  __syncthreads(); zeroAcc(); runUnit(wt + AW2T); __syncthreads();
    writeback(3, true);  __syncthreads(); zeroAcc(); runUnit(wt + AW3T); __syncthreads();

    // ---- final: logit = relu(acc + an_b3) . Wo + bo, straight from accumulators ----
    float p0 = 0.f, p1 = 0.f;
    {
        const float* b3p = &bias_all[4 * H_];
        const float* wop = &bias_all[5 * H_];
        #pragma unroll
        for (int q = 0; q < 4; ++q) {
            int n0 = ntile * 32 + q * 8 + oct * 4;
            float4 bq = *(const float4*)&b3p[n0];
            float4 wq = *(const float4*)&wop[n0];
            float ba[4] = {bq.x, bq.y, bq.z, bq.w};
            float wa[4] = {wq.x, wq.y, wq.z, wq.w};
            #pragma unroll
            for (int r2 = 0; r2 < 4; ++r2) {
                p0 += fmaxf(acc0[q * 4 + r2] + ba[r2], 0.f) * wa[r2];
                p1 += fmaxf(acc1[q * 4 + r2] + ba[r2], 0.f) * wa[r2];
            }
        }
    }
    p0 += __shfl_xor(p0, 32);
    p1 += __shfl_xor(p1, 32);
    if (l < 32) {
        red[ntile * H_ + mhalf * 64 + l31]      = p0;
        red[ntile * H_ + mhalf * 64 + 32 + l31] = p1;
    }
    __syncthreads();
    if (t < 128) {
        float sres = red[t] + red[H_ + t] + red[2 * H_ + t] + red[3 * H_ + t] + an_bo[0];
        int mg = blkTile * 128 + t;
        if (mg < M_)
            out[((size_t)(b * 3 + type)) * M_ + mg] = sres;
    }
}

extern "C" void kernel_launch(void* const* d_in, const int* in_sizes, int n_in,
                              void* d_out, int out_size, void* d_ws, size_t ws_size,
                              hipStream_t stream) {
    const float* e_emb     = (const float*)d_in[0];
    const int*   reloc_idx = (const int*)  d_in[1];
    const int*   cross_idx = (const int*)  d_in[2];
    const int*   twopt_idx = (const int*)  d_in[3];
    const float* reloc_W1  = (const float*)d_in[4];
    const float* reloc_b1  = (const float*)d_in[5];
    const float* reloc_W2  = (const float*)d_in[6];
    const float* reloc_b2  = (const float*)d_in[7];
    const float* cross_W1  = (const float*)d_in[8];
    const float* cross_b1  = (const float*)d_in[9];
    const float* cross_W2  = (const float*)d_in[10];
    const float* cross_b2  = (const float*)d_in[11];
    const float* an_W1     = (const float*)d_in[12];
    const float* an_b1     = (const float*)d_in[13];
    const float* an_W2     = (const float*)d_in[14];
    const float* an_b2     = (const float*)d_in[15];
    const float* an_W3     = (const float*)d_in[16];
    const float* an_b3     = (const float*)d_in[17];
    const float* an_Wo     = (const float*)d_in[18];
    const float* an_bo     = (const float*)d_in[19];
    float* out = (float*)d_out;
    unsigned short* wt = (unsigned short*)d_ws;   // needs ~983 KB of ws

    hipLaunchKernelGGL(wt_prep, dim3(960), dim3(256), 0, stream,
                       reloc_W1, reloc_W2, cross_W1, cross_W2, an_W1, an_W2, an_W3, wt);
    hipLaunchKernelGGL(vrp_mfma, dim3(3 * B_ * 16), dim3(NT), 0, stream,
                       e_emb, reloc_idx, cross_idx, twopt_idx,
                       reloc_b1, reloc_b2, cross_b1, cross_b2,
                       an_b1, an_b2, an_b3, an_Wo, an_bo, wt, out);
}